// Round 8
// baseline (717.108 us; speedup 1.0000x reference)
//
#include <hip/hip_runtime.h>
#include <stdint.h>

#define EMB 64
#define BN_EPS 1e-5f
#define TB_STRIDE 65
#define BSH 8              // bucket = 256 consecutive dst nodes
#define CHUNK 4096         // edges per k_part block

__device__ __forceinline__ unsigned short f2b(float x) {
    unsigned u = __float_as_uint(x);
    u += 0x7FFFu + ((u >> 16) & 1u);   // round-to-nearest-even
    return (unsigned short)(u >> 16);
}
__device__ __forceinline__ float b2f(unsigned short v) {
    return __uint_as_float(((unsigned)v) << 16);
}

// ---------------- zero init (ws is poisoned 0xAA every call) ----------------
__global__ void k_zero(int* __restrict__ bcnt, float* __restrict__ stats,
                       int nb, int nstats) {
    int i = blockIdx.x * blockDim.x + threadIdx.x;
    if (i < nb) bcnt[i] = 0;
    if (i < nstats) stats[i] = 0.0f;
}

// ---------------- bucket histogram (dst read once, LDS-combined) ----------
__global__ void __launch_bounds__(256) k_bhist(const int* __restrict__ ei,
                                               int* __restrict__ bcnt,
                                               int E, int nb) {
    __shared__ int lh[256];
    const int tid = threadIdx.x;
    lh[tid] = 0;
    __syncthreads();
    int stride = gridDim.x * blockDim.x;
    for (int e = blockIdx.x * blockDim.x + tid; e < E; e += stride)
        atomicAdd(&lh[((unsigned)ei[E + e]) >> BSH], 1);
    __syncthreads();
    if (tid < nb && lh[tid]) atomicAdd(&bcnt[tid], lh[tid]);
}

// ---------------- single-block bucket scan ----------------
__global__ void __launch_bounds__(256) k_bscan(const int* __restrict__ bcnt,
                                               int* __restrict__ bbase,
                                               int* __restrict__ bcur, int nb) {
    __shared__ int a[256];
    const int t = threadIdx.x;
    int v = (t < nb) ? bcnt[t] : 0;
    a[t] = v;
    __syncthreads();
    for (int off = 1; off < 256; off <<= 1) {
        int x = (t >= off) ? a[t - off] : 0;
        __syncthreads();
        a[t] += x;
        __syncthreads();
    }
    int excl = a[t] - v;
    if (t < nb) { bbase[t] = excl; bcur[t] = excl; }
    if (t == nb - 1) bbase[nb] = a[t];
}

// ---------------- phase 1: compact edges into per-bucket runs --------------
__global__ void __launch_bounds__(256) k_part(
        const int* __restrict__ ei, const float* __restrict__ ew,
        int* __restrict__ bcur, int2* __restrict__ eG, int E) {
    __shared__ int lcnt[256], lbase[256], loff[256];
    const int tid = threadIdx.x;
    const int c0 = blockIdx.x * CHUNK;
    lcnt[tid] = 0;
    __syncthreads();
    int src[16], pk[16], g[16];
    float wt[16];
#pragma unroll
    for (int i = 0; i < 16; i++) {
        int e = c0 + i * 256 + tid;
        if (e < E) {
            int d = ei[E + e];
            src[i] = ei[e];
            wt[i] = ew[e];
            g[i] = ((unsigned)d) >> BSH;
            pk[i] = src[i] | ((d & 255) << 24);
            atomicAdd(&lcnt[g[i]], 1);
        } else g[i] = -1;
    }
    __syncthreads();
    if (lcnt[tid]) lbase[tid] = atomicAdd(&bcur[tid], lcnt[tid]);
    loff[tid] = 0;
    __syncthreads();
#pragma unroll
    for (int i = 0; i < 16; i++) {
        if (g[i] >= 0) {
            int pos = lbase[g[i]] + atomicAdd(&loff[g[i]], 1);
            eG[pos] = make_int2(pk[i], __float_as_int(wt[i]));
        }
    }
}

// ---------------- phase 2: exact CSR inside each bucket --------------------
__global__ void __launch_bounds__(256) k_build(
        const int2* __restrict__ eG, const int* __restrict__ bbase,
        int* __restrict__ rowst, int* __restrict__ counts,
        int2* __restrict__ pairs, int N) {
    __shared__ int lcnt[256], a[256], lcur[256];
    const int t = threadIdx.x;
    const int b = blockIdx.x;
    const int e0 = bbase[b], e1 = bbase[b + 1];
    lcnt[t] = 0;
    __syncthreads();
    for (int i = e0 + t; i < e1; i += 256)
        atomicAdd(&lcnt[((unsigned)eG[i].x) >> 24], 1);
    __syncthreads();
    int v = lcnt[t];
    a[t] = v;
    __syncthreads();
    for (int off = 1; off < 256; off <<= 1) {
        int x = (t >= off) ? a[t - off] : 0;
        __syncthreads();
        a[t] += x;
        __syncthreads();
    }
    int excl = a[t] - v;
    lcur[t] = excl;
    int node = (b << BSH) + t;
    if (node < N) { rowst[node] = e0 + excl; counts[node] = v; }
    __syncthreads();
    for (int i = e0 + t; i < e1; i += 256) {
        int2 p = eG[i];
        int loc = ((unsigned)p.x) >> 24;
        int pos = e0 + atomicAdd(&lcur[loc], 1);
        pairs[pos] = make_int2(p.x & 0x00FFFFFF, p.y);
    }
}

// ---------------- aggregation: wave-per-node, lane=feature, bf16 gathers ----
__global__ void k_agg(const unsigned short* __restrict__ hb,
                      const float* __restrict__ h,
                      const int* __restrict__ rowst,
                      const int* __restrict__ counts, const int2* __restrict__ pairs,
                      float* __restrict__ out, int N) {
    const int lane = threadIdx.x & 63;
    int wave = (blockIdx.x * blockDim.x + threadIdx.x) >> 6;
    const int nwaves = (gridDim.x * blockDim.x) >> 6;
    for (int node = wave; node < N; node += nwaves) {
        int un = __builtin_amdgcn_readfirstlane(node);
        int s = rowst[un];
        int end = s + counts[un];
        float a0 = 0.f, a1 = 0.f, a2 = 0.f, a3 = 0.f;
        float a4 = 0.f, a5 = 0.f, a6 = 0.f, a7 = 0.f;
        for (int e = s; e < end; e += 8) {
#define SLOT(K, ACC)                                                       \
            {                                                              \
                int idx = e + K;                                           \
                bool ok = idx < end;                                       \
                int2 p = pairs[ok ? idx : s];                              \
                float w = ok ? __int_as_float(p.y) : 0.f;                  \
                float vv = b2f(hb[(size_t)p.x * EMB + lane]);              \
                ACC = fmaf(w, vv, ACC);                                    \
            }
            SLOT(0, a0) SLOT(1, a1) SLOT(2, a2) SLOT(3, a3)
            SLOT(4, a4) SLOT(5, a5) SLOT(6, a6) SLOT(7, a7)
#undef SLOT
        }
        float self = h[(size_t)un * EMB + lane];
        out[(size_t)un * EMB + lane] =
            (((a0 + a1) + (a2 + a3)) + ((a4 + a5) + (a6 + a7))) + self;
    }
}

// ---------------- matmul: block = one 64-node tile, 4 waves x 16 cols ------
// Staging: coalesced global->LDS with BN+relu applied (coeffs precomputed).
// Lane = node; row in VGPRs via conflict-free stride-65 scalar LDS reads.
// Wave wv computes cols [wv*16, wv*16+16); output staged back to LDS and
// flushed coalesced (+ optional bf16 pack). 3128 waves total (~12/CU).
template <bool BN_IN, bool DO_STATS, bool B16OUT>
__global__ void __launch_bounds__(256) k_mm(
                     const float* __restrict__ in, const float* __restrict__ W,
                     const float* __restrict__ bias, const float* __restrict__ stats,
                     const float* __restrict__ g, const float* __restrict__ be,
                     float invN, float* __restrict__ out, float* __restrict__ st_out,
                     unsigned short* __restrict__ b16out, int N) {
    __shared__ float tb[64 * TB_STRIDE];
    __shared__ float st_part[128];
    __shared__ float scs[EMB], shs[EMB];
    const int tid = threadIdx.x;
    const int lane = tid & 63;
    const int wv = tid >> 6;
    const int node0 = blockIdx.x * 64;
    const int nvalid = N - node0;   // >=1

    if (DO_STATS && tid < 128) st_part[tid] = 0.f;
    if (BN_IN && tid < EMB) {
        float m  = stats[tid] * invN;
        float va = fmaf(stats[EMB + tid], invN, -m * m);
        float rs = rsqrtf(va + BN_EPS);
        float sc = rs * g[tid];
        scs[tid] = sc;
        shs[tid] = fmaf(-m, sc, be[tid]);
    }
    if (BN_IN) __syncthreads();

    // stage input tile (coalesced), BN+relu applied element-wise
    const float4* in4 = (const float4*)(in + (size_t)node0 * EMB);
#pragma unroll
    for (int it = 0; it < 4; it++) {
        int flat4 = it * 256 + tid;
        int nsub = flat4 >> 4;
        int c4 = flat4 & 15;
        float4 v = (nsub < nvalid) ? in4[flat4] : make_float4(0.f, 0.f, 0.f, 0.f);
        if (BN_IN) {
            int f0 = c4 * 4;
            v.x = fmaxf(0.f, fmaf(v.x, scs[f0 + 0], shs[f0 + 0]));
            v.y = fmaxf(0.f, fmaf(v.y, scs[f0 + 1], shs[f0 + 1]));
            v.z = fmaxf(0.f, fmaf(v.z, scs[f0 + 2], shs[f0 + 2]));
            v.w = fmaxf(0.f, fmaf(v.w, scs[f0 + 3], shs[f0 + 3]));
        }
        float* d = tb + nsub * TB_STRIDE + c4 * 4;
        d[0] = v.x; d[1] = v.y; d[2] = v.z; d[3] = v.w;
    }
    __syncthreads();

    // lane = node: pull row into VGPRs (stride-65 scalar reads, 2-way = free)
    float row[EMB];
#pragma unroll
    for (int f = 0; f < EMB; f++) row[f] = tb[lane * TB_STRIDE + f];
    __syncthreads();   // all rows read before tb is overwritten

    // wave wv: 16 output cols
    const int j0 = wv * 16;           // uniform
    const bool vnode = lane < nvalid;
    float acc[16];
#pragma unroll
    for (int k = 0; k < 16; k++) acc[k] = bias[j0 + k];
#pragma unroll
    for (int f = 0; f < EMB; f++) {
        const float* wr = W + f * EMB + j0;   // uniform -> s_load
#pragma unroll
        for (int k = 0; k < 16; k++) acc[k] = fmaf(row[f], wr[k], acc[k]);
    }
#pragma unroll
    for (int k = 0; k < 16; k++)
        tb[lane * TB_STRIDE + j0 + k] = vnode ? acc[k] : 0.f;
    __syncthreads();

    // stats: wave wv walks 16 node rows, lane = feature (2-way = free)
    if (DO_STATS) {
        float s_sum = 0.f, s_sq = 0.f;
#pragma unroll
        for (int i = 0; i < 16; i++) {
            float v = tb[(wv * 16 + i) * TB_STRIDE + lane];
            s_sum += v;
            s_sq = fmaf(v, v, s_sq);
        }
        atomicAdd(&st_part[lane], s_sum);
        atomicAdd(&st_part[64 + lane], s_sq);
    }

    // coalesced flush (+ optional bf16 pack)
    float4* out4 = (float4*)(out + (size_t)node0 * EMB);
#pragma unroll
    for (int it = 0; it < 4; it++) {
        int flat4 = it * 256 + tid;
        int nsub = flat4 >> 4;
        int c4 = flat4 & 15;
        if (nsub < nvalid) {
            const float* s4 = tb + nsub * TB_STRIDE + c4 * 4;
            float4 o = make_float4(s4[0], s4[1], s4[2], s4[3]);
            out4[flat4] = o;
            if (B16OUT) {
                ushort4 ob;
                ob.x = f2b(o.x); ob.y = f2b(o.y);
                ob.z = f2b(o.z); ob.w = f2b(o.w);
                ((ushort4*)b16out)[(size_t)node0 * 16 + flat4] = ob;
            }
        }
    }

    if (DO_STATS) {
        __syncthreads();
        if (tid < 128) atomicAdd(&st_out[tid], st_part[tid]);
    }
}

// ---------------- outer BN + relu + residual (+ bf16 copy) ----------------
__global__ void k_bnres(const float* __restrict__ u, const float* __restrict__ st,
                        const float* __restrict__ g, const float* __restrict__ be,
                        const float* __restrict__ hin, float* __restrict__ hout,
                        unsigned short* __restrict__ b16out,
                        float invN, int total4) {
    int stride = gridDim.x * blockDim.x;
    for (int i4 = blockIdx.x * blockDim.x + threadIdx.x; i4 < total4; i4 += stride) {
        int c = i4 & 15;
        float4 uv = ((const float4*)u)[i4];
        float4 hv = ((const float4*)hin)[i4];
        float4 sv = ((const float4*)st)[c];
        float4 qv = ((const float4*)(st + EMB))[c];
        float4 gv = ((const float4*)g)[c];
        float4 bv = ((const float4*)be)[c];
        float4 o;
#define BNR(comp)                                                     \
        {                                                             \
            float m  = sv.comp * invN;                                \
            float va = fmaf(qv.comp, invN, -m * m);                   \
            float rs = rsqrtf(va + BN_EPS);                           \
            float sc = rs * gv.comp;                                  \
            float sh = fmaf(-m, sc, bv.comp);                         \
            float r  = fmaxf(0.f, fmaf(uv.comp, sc, sh));             \
            o.comp = r + hv.comp;                                     \
        }
        BNR(x) BNR(y) BNR(z) BNR(w)
#undef BNR
        ((float4*)hout)[i4] = o;
        if (b16out) {
            ushort4 ob;
            ob.x = f2b(o.x); ob.y = f2b(o.y);
            ob.z = f2b(o.z); ob.w = f2b(o.w);
            ((ushort4*)b16out)[i4] = ob;
        }
    }
}

// ---------------- launcher ----------------
extern "C" void kernel_launch(void* const* d_in, const int* in_sizes, int n_in,
                              void* d_out, int out_size, void* d_ws, size_t ws_size,
                              hipStream_t stream) {
    const float* x     = (const float*)d_in[0];
    const int*   ei    = (const int*)d_in[1];
    const float* ew    = (const float*)d_in[3];
    const float* ae_w  = (const float*)d_in[4];
    const float* ae_b  = (const float*)d_in[5];
    const float* W1    = (const float*)d_in[6];
    const float* b1    = (const float*)d_in[7];
    const float* g1    = (const float*)d_in[8];
    const float* be1   = (const float*)d_in[9];
    const float* W2    = (const float*)d_in[10];
    const float* b2    = (const float*)d_in[11];
    const float* g_out = (const float*)d_in[12];
    const float* be_out= (const float*)d_in[13];

    const int N = in_sizes[0] / EMB;
    const int E = in_sizes[3];
    const int L = in_sizes[6] / (EMB * EMB);
    const float invN = 1.0f / (float)N;
    const int NBUCK = (N + 255) >> BSH;

    uintptr_t p = (uintptr_t)d_ws;
    auto alloc = [&](size_t bytes) -> void* {
        p = (p + 255) & ~(uintptr_t)255;
        void* r = (void*)p;
        p += bytes;
        return r;
    };
    float* h     = (float*)alloc((size_t)N * EMB * 4);
    float* bufa  = (float*)alloc((size_t)N * EMB * 4);
    float* buft  = (float*)alloc((size_t)N * EMB * 4);  // also hosts staged edges
    unsigned short* hb16 = (unsigned short*)alloc((size_t)N * EMB * 2);
    int*   counts= (int*)alloc((size_t)N * 4);
    int*   rowst = (int*)alloc((size_t)N * 4);
    int*   bcnt  = (int*)alloc(256 * 4);
    int*   bbase = (int*)alloc(257 * 4);
    int*   bcur  = (int*)alloc(256 * 4);
    int2*  pairs = (int2*)alloc((size_t)E * 8);
    float* stats = (float*)alloc((size_t)L * 2 * 2 * EMB * 4);
    int2*  eG    = (int2*)buft;
    (void)ws_size; (void)n_in; (void)out_size;

    const int nstats = L * 2 * 2 * EMB;
    int zgrid = ((NBUCK > nstats ? NBUCK : nstats) + 255) / 256;
    hipLaunchKernelGGL(k_zero, dim3(zgrid), dim3(256), 0, stream,
                       bcnt, stats, NBUCK, nstats);

    const int ntiles = (N + 63) / 64;
    // encoder: h = x @ ae_w + ae_b   (+ bf16 copy)
    hipLaunchKernelGGL((k_mm<false, false, true>), dim3(ntiles), dim3(256), 0, stream,
                       x, ae_w, ae_b, (const float*)nullptr, (const float*)nullptr,
                       (const float*)nullptr, 0.f, h, (float*)nullptr, hb16, N);

    // CSR build: bucket hist -> scan -> compact -> per-bucket exact CSR
    hipLaunchKernelGGL(k_bhist, dim3(120), dim3(256), 0, stream, ei, bcnt, E, NBUCK);
    hipLaunchKernelGGL(k_bscan, dim3(1), dim3(256), 0, stream, bcnt, bbase, bcur, NBUCK);
    hipLaunchKernelGGL(k_part, dim3((E + CHUNK - 1) / CHUNK), dim3(256), 0, stream,
                       ei, ew, bcur, eG, E);
    hipLaunchKernelGGL(k_build, dim3(NBUCK), dim3(256), 0, stream,
                       eG, bbase, rowst, counts, pairs, N);

    for (int l = 0; l < L; l++) {
        float* stats1 = stats + (size_t)(l * 2 + 0) * 2 * EMB;
        float* stats2 = stats + (size_t)(l * 2 + 1) * 2 * EMB;

        // agg + self  (bf16 gathers)
        hipLaunchKernelGGL(k_agg, dim3(2048), dim3(256), 0, stream,
                           hb16, h, rowst, counts, pairs, bufa, N);
        // t = agg @ W1 + b1   (+stats1)
        hipLaunchKernelGGL((k_mm<false, true, false>), dim3(ntiles), dim3(256), 0, stream,
                           bufa, W1 + (size_t)l * EMB * EMB, b1 + (size_t)l * EMB,
                           (const float*)nullptr, (const float*)nullptr,
                           (const float*)nullptr, 0.f, buft, stats1,
                           (unsigned short*)nullptr, N);
        // u = relu(bn1(t)) @ W2 + b2   (+stats2)
        hipLaunchKernelGGL((k_mm<true, true, false>), dim3(ntiles), dim3(256), 0, stream,
                           buft, W2 + (size_t)l * EMB * EMB, b2 + (size_t)l * EMB,
                           stats1, g1 + (size_t)l * EMB, be1 + (size_t)l * EMB,
                           invN, bufa, stats2, (unsigned short*)nullptr, N);
        // h = relu(bn2(u)) + h   (+ bf16 copy for next layer's gathers)
        float* hout = (l == L - 1) ? (float*)d_out : h;
        unsigned short* b16o = (l == L - 1) ? (unsigned short*)nullptr : hb16;
        hipLaunchKernelGGL(k_bnres, dim3(1024), dim3(256), 0, stream,
                           bufa, stats2, g_out + (size_t)l * EMB, be_out + (size_t)l * EMB,
                           h, hout, b16o, invN, N * 16);
    }
}